// Round 1
// baseline (2133.370 us; speedup 1.0000x reference)
//
#include <hip/hip_runtime.h>
#include <stdint.h>

#define NB 16
#define NS 256
#define NV 32000
#define NE 512
#define NH 1024
#define PAD_IDX 3

// workspace byte offsets
#define WS_XP    0L                 // f32 [4096][1024]   16,777,216 B
#define WS_HCH   16777216L          // bf16 [257][16][1024] 8,421,376 B
#define WS_WHO   25198592L          // bf16 [32000][1024] 65,536,000 B
#define WS_FLAGS 90734592L          // u32 [256][64]          65,536 B
#define WS_NEED  90800128L

typedef __attribute__((ext_vector_type(8))) short bf16x8;
typedef __attribute__((ext_vector_type(4))) float f32x4;
typedef __attribute__((ext_vector_type(4))) uint32_t u32x4;

__device__ __forceinline__ uint16_t f2bf(float f){
  union { float f; uint32_t u; } v; v.f = f;
  return (uint16_t)((v.u + 0x7fffu + ((v.u >> 16) & 1u)) >> 16);  // RNE
}

__device__ __forceinline__ bf16x8 pack8(float4 a, float4 b){
  bf16x8 r;
  r[0]=(short)f2bf(a.x); r[1]=(short)f2bf(a.y); r[2]=(short)f2bf(a.z); r[3]=(short)f2bf(a.w);
  r[4]=(short)f2bf(b.x); r[5]=(short)f2bf(b.y); r[6]=(short)f2bf(b.z); r[7]=(short)f2bf(b.w);
  return r;
}

// ---- K0: zero barrier flags, convert initial hidden -> hchain slot 0 (bf16)
__global__ void k_init(const float* __restrict__ hidden, uint16_t* __restrict__ hch0,
                       uint32_t* __restrict__ flags){
  int idx = blockIdx.x * 256 + threadIdx.x;   // grid 64*256 = 16384 exactly
  flags[idx] = 0u;                            // 256 steps * 64 blocks
  hch0[idx]  = f2bf(hidden[idx]);             // 16*1024
}

// ---- K1: Who_w f32 -> bf16 (row-major [32000][1024])
__global__ void k_cvt(const float* __restrict__ src, uint32_t* __restrict__ dst){
  long idx = (long)blockIdx.x * 256 + threadIdx.x;  // 4,096,000 threads, 8 f32 each
  const float4* p = (const float4*)src;
  float4 a = p[idx*2], b = p[idx*2+1];
  u32x4 d;
  d[0] = (uint32_t)f2bf(a.x) | ((uint32_t)f2bf(a.y) << 16);
  d[1] = (uint32_t)f2bf(a.z) | ((uint32_t)f2bf(a.w) << 16);
  d[2] = (uint32_t)f2bf(b.x) | ((uint32_t)f2bf(b.y) << 16);
  d[3] = (uint32_t)f2bf(b.z) | ((uint32_t)f2bf(b.w) << 16);
  ((u32x4*)dst)[idx] = d;
}

// ---- K2: xp[m][n] = sum_k emb(ids[m])[k] * Wxh[n][k] + b[n]   (m=(b,s), bf16 MFMA)
__global__ __launch_bounds__(256) void k_xproj(
    const int* __restrict__ ids, const float* __restrict__ tab,
    const float* __restrict__ wxh, const float* __restrict__ bxh,
    float* __restrict__ xp){
  int bid = blockIdx.x;                 // 64 M-tiles x 16 N-tiles
  int tm = bid & 63, tn = bid >> 6;
  int Mb = tm * 64, Nb = tn * 64;
  int tid = threadIdx.x;
  int w = tid >> 6, l = tid & 63;
  int lr = l & 15, lk = l >> 4;

  int m = Mb + w*16 + lr;
  int id = ids[m];
  const float* arow = tab + (long)id * NE;
  bool pad = (id == PAD_IDX);

  f32x4 acc[4];
  #pragma unroll
  for (int j = 0; j < 4; ++j) acc[j] = (f32x4){0.f,0.f,0.f,0.f};

  for (int k0 = 0; k0 < NE; k0 += 32){
    int k = k0 + lk*8;
    bf16x8 af = (bf16x8){0,0,0,0,0,0,0,0};
    if (!pad){
      float4 a = *(const float4*)(arow + k);
      float4 b = *(const float4*)(arow + k + 4);
      af = pack8(a, b);
    }
    #pragma unroll
    for (int j = 0; j < 4; ++j){
      const float* brow = wxh + (long)(Nb + j*16 + lr) * NE + k;
      float4 x = *(const float4*)brow;
      float4 y = *(const float4*)(brow + 4);
      bf16x8 bf_ = pack8(x, y);
      acc[j] = __builtin_amdgcn_mfma_f32_16x16x32_bf16(af, bf_, acc[j], 0, 0, 0);
    }
  }
  #pragma unroll
  for (int j = 0; j < 4; ++j){
    int n = Nb + j*16 + lr;
    float bias = bxh[n];
    #pragma unroll
    for (int r = 0; r < 4; ++r){
      int row = Mb + w*16 + lk*4 + r;
      xp[(long)row * NH + n] = acc[j][r] + bias;
    }
  }
}

// ---- K3: persistent recurrence. 64 blocks x 1 wave; block owns 16 hidden cols.
// Per step: stage h_t (bf16) -> LDS, MFMA (M=batch16, N=16 cols, K=1024), tanh,
// write h_{t+1} slice, release flag, spin on all 64 flags (lane i : flag i).
__global__ __launch_bounds__(64) void k_rnn(
    const float* __restrict__ whh, const float* __restrict__ xp,
    uint16_t* __restrict__ hch, uint32_t* __restrict__ flags,
    float* __restrict__ hfin){
  __shared__ __align__(16) uint16_t whh_s[16*1024];  // bf16, 16B-chunk xor-swizzled
  __shared__ __align__(16) uint16_t h_s[16*1024];
  const int blk = blockIdx.x;     // 0..63
  const int l   = threadIdx.x;    // 0..63
  const int j0  = blk * 16;
  const int lr = l & 15, lk = l >> 4;

  // stage Whh rows [j0, j0+16) as bf16, swizzle chunk c -> c^(row&7)
  for (int it = 0; it < 32; ++it){
    int chunk = it*64 + l;        // 0..2047 = row*128 + c
    int row = chunk >> 7, c = chunk & 127;
    const float* s0 = whh + (long)(j0 + row) * NH + c*8;
    float4 a = *(const float4*)s0;
    float4 b = *(const float4*)(s0 + 4);
    u32x4 d;
    d[0] = (uint32_t)f2bf(a.x) | ((uint32_t)f2bf(a.y) << 16);
    d[1] = (uint32_t)f2bf(a.z) | ((uint32_t)f2bf(a.w) << 16);
    d[2] = (uint32_t)f2bf(b.x) | ((uint32_t)f2bf(b.y) << 16);
    d[3] = (uint32_t)f2bf(b.z) | ((uint32_t)f2bf(b.w) << 16);
    ((u32x4*)whh_s)[row*128 + (c ^ (row & 7))] = d;
  }

  for (int t = 0; t < NS; ++t){
    // stage h_t: issue all 32 loads first (latency), then LDS writes
    const u32x4* hsrc = (const u32x4*)(hch + (long)t * NB * NH);
    u32x4 hreg[32];
    #pragma unroll
    for (int it = 0; it < 32; ++it) hreg[it] = hsrc[it*64 + l];
    #pragma unroll
    for (int it = 0; it < 32; ++it){
      int chunk = it*64 + l;
      int row = chunk >> 7, c = chunk & 127;
      ((u32x4*)h_s)[row*128 + (c ^ (row & 7))] = hreg[it];
    }
    __syncthreads();

    f32x4 acc0 = (f32x4){0.f,0.f,0.f,0.f}, acc1 = (f32x4){0.f,0.f,0.f,0.f};
    #pragma unroll
    for (int kk = 0; kk < 32; kk += 2){
      int c0 = kk*4 + lk, c1 = c0 + 4;
      bf16x8 a0 = *(const bf16x8*)&((const u32x4*)h_s)  [lr*128 + (c0 ^ (lr & 7))];
      bf16x8 b0 = *(const bf16x8*)&((const u32x4*)whh_s)[lr*128 + (c0 ^ (lr & 7))];
      acc0 = __builtin_amdgcn_mfma_f32_16x16x32_bf16(a0, b0, acc0, 0, 0, 0);
      bf16x8 a1 = *(const bf16x8*)&((const u32x4*)h_s)  [lr*128 + (c1 ^ (lr & 7))];
      bf16x8 b1 = *(const bf16x8*)&((const u32x4*)whh_s)[lr*128 + (c1 ^ (lr & 7))];
      acc1 = __builtin_amdgcn_mfma_f32_16x16x32_bf16(a1, b1, acc1, 0, 0, 0);
    }
    f32x4 acc = acc0 + acc1;

    uint16_t* hdst = hch + (long)(t+1) * NB * NH;
    #pragma unroll
    for (int r = 0; r < 4; ++r){
      int b = lk*4 + r;                               // C/D: row=(l>>4)*4+r, col=l&15
      float x = xp[((long)b * NS + t) * NH + (j0 + lr)];
      float hv = tanhf(x + acc[r]);
      hdst[b*NH + j0 + lr] = f2bf(hv);
      if (t == NS-1) hfin[b*NH + j0 + lr] = hv;
    }
    // publish slice, wait for all blocks (lane i watches flag i), acquire
    if (l == 0)
      __hip_atomic_store(&flags[t*64 + blk], 1u, __ATOMIC_RELEASE, __HIP_MEMORY_SCOPE_AGENT);
    while (__hip_atomic_load(&flags[t*64 + l], __ATOMIC_RELAXED, __HIP_MEMORY_SCOPE_AGENT) == 0u)
      __builtin_amdgcn_s_sleep(1);
    __threadfence();
    __syncthreads();
  }
}

// ---- K4: logits = h_all * Who^T + b. 128x128 tile, BK=32, 4 waves 2x2, bf16 MFMA.
__global__ __launch_bounds__(256) void k_logits(
    const uint16_t* __restrict__ hch, const uint16_t* __restrict__ whobf,
    const float* __restrict__ whob, float* __restrict__ out){
  __shared__ __align__(16) uint16_t As[128*32];
  __shared__ __align__(16) uint16_t Bs[128*32];
  int bid = blockIdx.x;                      // 8000 = 32 Mtiles * 250 Ntiles
  int swz = (bid & 7) * 1000 + (bid >> 3);   // XCD-aware (8000 % 8 == 0, bijective)
  int tm = swz & 31, tn = swz >> 5;
  int Mb = tm * 128, Nb = tn * 128;
  int tid = threadIdx.x;
  int w = tid >> 6, l = tid & 63;
  int wm = w >> 1, wn = w & 1;
  int lr = l & 15, lk = l >> 4;

  // staging: thread owns chunks (r0,c0) and (r0+64,c0) of both tiles
  int r0 = tid >> 2, c0 = tid & 3;
  int r1 = r0 + 64;
  int m0 = Mb + r0, m1 = Mb + r1;            // A row -> (b=m>>8, s=m&255), slot s+1
  const uint16_t* pa0 = hch + ((long)((m0 & 255) + 1) * 16 + (m0 >> 8)) * NH + c0*8;
  const uint16_t* pa1 = hch + ((long)((m1 & 255) + 1) * 16 + (m1 >> 8)) * NH + c0*8;
  const uint16_t* pb0 = whobf + (long)(Nb + r0) * NH + c0*8;
  const uint16_t* pb1 = whobf + (long)(Nb + r1) * NH + c0*8;
  int da0 = r0*4 + (c0 ^ (r0 & 3));
  int da1 = r1*4 + (c0 ^ (r1 & 3));

  u32x4 ra0 = *(const u32x4*)pa0;
  u32x4 ra1 = *(const u32x4*)pa1;
  u32x4 rb0 = *(const u32x4*)pb0;
  u32x4 rb1 = *(const u32x4*)pb1;

  f32x4 acc[4][4];
  #pragma unroll
  for (int i = 0; i < 4; ++i)
    #pragma unroll
    for (int j = 0; j < 4; ++j) acc[i][j] = (f32x4){0.f,0.f,0.f,0.f};

  for (int kt = 0; kt < 32; ++kt){
    ((u32x4*)As)[da0] = ra0;
    ((u32x4*)As)[da1] = ra1;
    ((u32x4*)Bs)[da0] = rb0;
    ((u32x4*)Bs)[da1] = rb1;
    __syncthreads();
    if (kt != 31){
      int off = (kt + 1) * 32;
      ra0 = *(const u32x4*)(pa0 + off);
      ra1 = *(const u32x4*)(pa1 + off);
      rb0 = *(const u32x4*)(pb0 + off);
      rb1 = *(const u32x4*)(pb1 + off);
    }
    bf16x8 af[4], bg[4];
    #pragma unroll
    for (int i = 0; i < 4; ++i){
      int r  = wm*64 + i*16 + lr;
      int rb = wn*64 + i*16 + lr;
      af[i] = *(const bf16x8*)&((const u32x4*)As)[r*4  + (lk ^ (r  & 3))];
      bg[i] = *(const bf16x8*)&((const u32x4*)Bs)[rb*4 + (lk ^ (rb & 3))];
    }
    #pragma unroll
    for (int i = 0; i < 4; ++i)
      #pragma unroll
      for (int j = 0; j < 4; ++j)
        acc[i][j] = __builtin_amdgcn_mfma_f32_16x16x32_bf16(af[i], bg[j], acc[i][j], 0, 0, 0);
    __syncthreads();
  }

  #pragma unroll
  for (int j = 0; j < 4; ++j){
    int col = Nb + wn*64 + j*16 + lr;
    float bias = whob[col];
    #pragma unroll
    for (int i = 0; i < 4; ++i){
      #pragma unroll
      for (int r = 0; r < 4; ++r){
        int row = Mb + wm*64 + i*16 + lk*4 + r;
        out[(long)row * NV + col] = acc[i][j][r] + bias;
      }
    }
  }
}

extern "C" void kernel_launch(void* const* d_in, const int* in_sizes, int n_in,
                              void* d_out, int out_size, void* d_ws, size_t ws_size,
                              hipStream_t stream){
  (void)in_sizes; (void)n_in; (void)out_size;
  if (ws_size < (size_t)WS_NEED) return;   // insufficient scratch -> fail loudly (poison stays)

  const int*   ids    = (const int*)  d_in[0];
  const float* hidden = (const float*)d_in[1];
  const float* table  = (const float*)d_in[2];
  const float* wxh    = (const float*)d_in[3];
  const float* bxh    = (const float*)d_in[4];
  const float* whh    = (const float*)d_in[5];
  const float* who    = (const float*)d_in[6];
  const float* whob   = (const float*)d_in[7];

  char* ws = (char*)d_ws;
  float*    xp     = (float*)   (ws + WS_XP);
  uint16_t* hchain = (uint16_t*)(ws + WS_HCH);
  uint16_t* whobf  = (uint16_t*)(ws + WS_WHO);
  uint32_t* flags  = (uint32_t*)(ws + WS_FLAGS);
  float* out    = (float*)d_out;
  float* hfinal = out + (long)NB * NS * NV;   // 131,072,000

  k_init  <<<64,    256, 0, stream>>>(hidden, hchain, flags);
  k_cvt   <<<16000, 256, 0, stream>>>(who, (uint32_t*)whobf);
  k_xproj <<<1024,  256, 0, stream>>>(ids, table, wxh, bxh, xp);
  k_rnn   <<<64,    64,  0, stream>>>(whh, xp, hchain, flags, hfinal);
  k_logits<<<8000,  256, 0, stream>>>(hchain, whobf, whob, out);
}

// Round 2
// 1602.364 us; speedup vs baseline: 1.3314x; 1.3314x over previous
//
#include <hip/hip_runtime.h>
#include <stdint.h>

#define NB 16
#define NS 256
#define NV 32000
#define NE 512
#define NH 1024
#define PAD_IDX 3

// workspace byte offsets
#define WS_XP    0L                 // f32 [4096][1024]   16,777,216 B
#define WS_HCH   16777216L          // bf16 [257][16][1024] 8,421,376 B
#define WS_WHO   25198592L          // bf16 [32000][1024] 65,536,000 B
#define WS_FLAGS 90734592L          // u32 [256][64]          65,536 B
#define WS_NEED  90800128L

typedef __attribute__((ext_vector_type(8))) short bf16x8;
typedef __attribute__((ext_vector_type(4))) float f32x4;
typedef __attribute__((ext_vector_type(4))) uint32_t u32x4;

__device__ __forceinline__ uint16_t f2bf(float f){
  union { float f; uint32_t u; } v; v.f = f;
  return (uint16_t)((v.u + 0x7fffu + ((v.u >> 16) & 1u)) >> 16);  // RNE
}

__device__ __forceinline__ bf16x8 pack8(float4 a, float4 b){
  bf16x8 r;
  r[0]=(short)f2bf(a.x); r[1]=(short)f2bf(a.y); r[2]=(short)f2bf(a.z); r[3]=(short)f2bf(a.w);
  r[4]=(short)f2bf(b.x); r[5]=(short)f2bf(b.y); r[6]=(short)f2bf(b.z); r[7]=(short)f2bf(b.w);
  return r;
}

// coherent (device-scope) 16B load: bypasses L1/L2, reads the coherence point
__device__ __forceinline__ u32x4 load_coh16(const void* p){
  u32x4 r;
  asm volatile("global_load_dwordx4 %0, %1, off sc0 sc1" : "=v"(r) : "v"(p) : "memory");
  return r;
}
// coherent write-through 8B store
__device__ __forceinline__ void store_coh8(void* p, uint64_t v){
  asm volatile("global_store_dwordx2 %0, %1, off sc0 sc1" :: "v"(p), "v"(v) : "memory");
}

// ---- K0: zero barrier flags, convert initial hidden -> hchain slot 0 (bf16)
__global__ void k_init(const float* __restrict__ hidden, uint16_t* __restrict__ hch0,
                       uint32_t* __restrict__ flags){
  int idx = blockIdx.x * 256 + threadIdx.x;   // grid 64*256 = 16384 exactly
  flags[idx] = 0u;                            // 256 steps * 64 blocks
  hch0[idx]  = f2bf(hidden[idx]);             // 16*1024
}

// ---- K1: Who_w f32 -> bf16 (row-major [32000][1024])
__global__ void k_cvt(const float* __restrict__ src, uint32_t* __restrict__ dst){
  long idx = (long)blockIdx.x * 256 + threadIdx.x;  // 4,096,000 threads, 8 f32 each
  const float4* p = (const float4*)src;
  float4 a = p[idx*2], b = p[idx*2+1];
  u32x4 d;
  d[0] = (uint32_t)f2bf(a.x) | ((uint32_t)f2bf(a.y) << 16);
  d[1] = (uint32_t)f2bf(a.z) | ((uint32_t)f2bf(a.w) << 16);
  d[2] = (uint32_t)f2bf(b.x) | ((uint32_t)f2bf(b.y) << 16);
  d[3] = (uint32_t)f2bf(b.z) | ((uint32_t)f2bf(b.w) << 16);
  ((u32x4*)dst)[idx] = d;
}

// ---- K2: xp[m][n] = sum_k emb(ids[m])[k] * Wxh[n][k] + b[n]   (m=(b,s), bf16 MFMA)
__global__ __launch_bounds__(256) void k_xproj(
    const int* __restrict__ ids, const float* __restrict__ tab,
    const float* __restrict__ wxh, const float* __restrict__ bxh,
    float* __restrict__ xp){
  int bid = blockIdx.x;                 // 64 M-tiles x 16 N-tiles
  int tm = bid & 63, tn = bid >> 6;
  int Mb = tm * 64, Nb = tn * 64;
  int tid = threadIdx.x;
  int w = tid >> 6, l = tid & 63;
  int lr = l & 15, lk = l >> 4;

  int m = Mb + w*16 + lr;
  int id = ids[m];
  const float* arow = tab + (long)id * NE;
  bool pad = (id == PAD_IDX);

  f32x4 acc[4];
  #pragma unroll
  for (int j = 0; j < 4; ++j) acc[j] = (f32x4){0.f,0.f,0.f,0.f};

  for (int k0 = 0; k0 < NE; k0 += 32){
    int k = k0 + lk*8;
    bf16x8 af = (bf16x8){0,0,0,0,0,0,0,0};
    if (!pad){
      float4 a = *(const float4*)(arow + k);
      float4 b = *(const float4*)(arow + k + 4);
      af = pack8(a, b);
    }
    #pragma unroll
    for (int j = 0; j < 4; ++j){
      const float* brow = wxh + (long)(Nb + j*16 + lr) * NE + k;
      float4 x = *(const float4*)brow;
      float4 y = *(const float4*)(brow + 4);
      bf16x8 bf_ = pack8(x, y);
      acc[j] = __builtin_amdgcn_mfma_f32_16x16x32_bf16(af, bf_, acc[j], 0, 0, 0);
    }
  }
  #pragma unroll
  for (int j = 0; j < 4; ++j){
    int n = Nb + j*16 + lr;
    float bias = bxh[n];
    #pragma unroll
    for (int r = 0; r < 4; ++r){
      int row = Mb + w*16 + lk*4 + r;
      xp[(long)row * NH + n] = acc[j][r] + bias;
    }
  }
}

// ---- K3: persistent recurrence. 64 blocks x 1 wave; block owns 16 hidden cols.
// Per step: coherent-load A-fragments of h_t directly (sc0sc1, no LDS round trip),
// MFMA (M=16 batch, N=16 cols, K=1024), tanh, transpose 16x16 slice in LDS,
// write-through store, vmcnt(0), relaxed flag release, xp prefetch, spin (no fences).
__global__ __launch_bounds__(64) void k_rnn(
    const float* __restrict__ whh, const float* __restrict__ xp,
    uint16_t* __restrict__ hch, uint32_t* __restrict__ flags,
    float* __restrict__ hfin){
  __shared__ __align__(16) uint16_t whh_s[16*1024];  // bf16, 16B-chunk xor-swizzled
  __shared__ __align__(16) uint16_t hs2[16*16];      // output transpose buffer
  const int blk = blockIdx.x;     // 0..63
  const int l   = threadIdx.x;    // 0..63
  const int j0  = blk * 16;
  const int lr = l & 15, lk = l >> 4;

  // stage Whh rows [j0, j0+16) as bf16, swizzle chunk c -> c^(row&7)
  for (int it = 0; it < 32; ++it){
    int chunk = it*64 + l;        // 0..2047 = row*128 + c
    int row = chunk >> 7, c = chunk & 127;
    const float* s0 = whh + (long)(j0 + row) * NH + c*8;
    float4 a = *(const float4*)s0;
    float4 b = *(const float4*)(s0 + 4);
    u32x4 d;
    d[0] = (uint32_t)f2bf(a.x) | ((uint32_t)f2bf(a.y) << 16);
    d[1] = (uint32_t)f2bf(a.z) | ((uint32_t)f2bf(a.w) << 16);
    d[2] = (uint32_t)f2bf(b.x) | ((uint32_t)f2bf(b.y) << 16);
    d[3] = (uint32_t)f2bf(b.z) | ((uint32_t)f2bf(b.w) << 16);
    ((u32x4*)whh_s)[row*128 + (c ^ (row & 7))] = d;
  }
  __syncthreads();

  // prefetch xp for t=0 (normal cached loads)
  float xpreg[4];
  #pragma unroll
  for (int r = 0; r < 4; ++r){
    int b = lk*4 + r;
    xpreg[r] = xp[((long)b * NS + 0) * NH + j0 + lr];
  }

  const char* hbase = (const char*)hch;
  for (int t = 0; t < NS; ++t){
    // direct coherent loads of this lane's A-fragments:
    // h[batch=lr][k = kk*32 + lk*8 .. +7]  (16B each, 32 per lane)
    const char* hsrc = hbase + (long)t * NB * NH * 2 + lr * 2048 + lk * 16;
    u32x4 hfrag[32];
    #pragma unroll
    for (int kk = 0; kk < 32; ++kk)
      hfrag[kk] = load_coh16(hsrc + kk * 64);
    asm volatile("s_waitcnt vmcnt(0)" ::: "memory");
    __builtin_amdgcn_sched_barrier(0);

    f32x4 a0 = (f32x4){0.f,0.f,0.f,0.f}, a1 = a0, a2 = a0, a3 = a0;
    #pragma unroll
    for (int kk = 0; kk < 32; kk += 4){
      int c0 = kk*4 + lk;
      bf16x8 b0 = *(const bf16x8*)&((const u32x4*)whh_s)[lr*128 + ( c0      ^ (lr & 7))];
      bf16x8 b1 = *(const bf16x8*)&((const u32x4*)whh_s)[lr*128 + ((c0 + 4) ^ (lr & 7))];
      bf16x8 b2 = *(const bf16x8*)&((const u32x4*)whh_s)[lr*128 + ((c0 + 8) ^ (lr & 7))];
      bf16x8 b3 = *(const bf16x8*)&((const u32x4*)whh_s)[lr*128 + ((c0 +12) ^ (lr & 7))];
      a0 = __builtin_amdgcn_mfma_f32_16x16x32_bf16(*(const bf16x8*)&hfrag[kk  ], b0, a0, 0, 0, 0);
      a1 = __builtin_amdgcn_mfma_f32_16x16x32_bf16(*(const bf16x8*)&hfrag[kk+1], b1, a1, 0, 0, 0);
      a2 = __builtin_amdgcn_mfma_f32_16x16x32_bf16(*(const bf16x8*)&hfrag[kk+2], b2, a2, 0, 0, 0);
      a3 = __builtin_amdgcn_mfma_f32_16x16x32_bf16(*(const bf16x8*)&hfrag[kk+3], b3, a3, 0, 0, 0);
    }
    f32x4 acc = (a0 + a1) + (a2 + a3);

    // tanh + transpose through tiny LDS buffer (C/D: row=(l>>4)*4+r, col=l&15)
    #pragma unroll
    for (int r = 0; r < 4; ++r){
      int b = lk*4 + r;
      float hv = tanhf(xpreg[r] + acc[r]);
      hs2[b*16 + lr] = f2bf(hv);
      if (t == NS-1) hfin[b*NH + j0 + lr] = hv;
    }
    __syncthreads();

    // coalesced write-through store: lane l -> batch row l>>2, col chunk l&3 (4 bf16)
    {
      int rb = l >> 2, cc = l & 3;
      uint32_t w0 = *(const uint32_t*)&hs2[rb*16 + cc*4];
      uint32_t w1 = *(const uint32_t*)&hs2[rb*16 + cc*4 + 2];
      char* dst = (char*)hch + (long)(t+1) * NB * NH * 2 + rb * 2048 + j0*2 + cc*8;
      store_coh8(dst, ((uint64_t)w1 << 32) | (uint64_t)w0);
    }

    if (t + 1 < NS){
      asm volatile("s_waitcnt vmcnt(0)" ::: "memory");   // data acked at coherence point
      if (l == 0)
        __hip_atomic_store(&flags[t*64 + blk], 1u, __ATOMIC_RELAXED, __HIP_MEMORY_SCOPE_AGENT);
      // prefetch xp for t+1 while spinning
      #pragma unroll
      for (int r = 0; r < 4; ++r){
        int b = lk*4 + r;
        xpreg[r] = xp[((long)b * NS + (t+1)) * NH + j0 + lr];
      }
      while (__hip_atomic_load(&flags[t*64 + l], __ATOMIC_RELAXED, __HIP_MEMORY_SCOPE_AGENT) == 0u)
        __builtin_amdgcn_s_sleep(1);
    }
    __syncthreads();   // protect hs2 reuse across iterations (1 wave, cheap)
  }
}

// ---- K4: logits = h_all * Who^T + b. 128x128 tile, BK=32, 4 waves 2x2, bf16 MFMA.
__global__ __launch_bounds__(256) void k_logits(
    const uint16_t* __restrict__ hch, const uint16_t* __restrict__ whobf,
    const float* __restrict__ whob, float* __restrict__ out){
  __shared__ __align__(16) uint16_t As[128*32];
  __shared__ __align__(16) uint16_t Bs[128*32];
  int bid = blockIdx.x;                      // 8000 = 32 Mtiles * 250 Ntiles
  int swz = (bid & 7) * 1000 + (bid >> 3);   // XCD-aware (8000 % 8 == 0, bijective)
  int tm = swz & 31, tn = swz >> 5;
  int Mb = tm * 128, Nb = tn * 128;
  int tid = threadIdx.x;
  int w = tid >> 6, l = tid & 63;
  int wm = w >> 1, wn = w & 1;
  int lr = l & 15, lk = l >> 4;

  // staging: thread owns chunks (r0,c0) and (r0+64,c0) of both tiles
  int r0 = tid >> 2, c0 = tid & 3;
  int r1 = r0 + 64;
  int m0 = Mb + r0, m1 = Mb + r1;            // A row -> (b=m>>8, s=m&255), slot s+1
  const uint16_t* pa0 = hch + ((long)((m0 & 255) + 1) * 16 + (m0 >> 8)) * NH + c0*8;
  const uint16_t* pa1 = hch + ((long)((m1 & 255) + 1) * 16 + (m1 >> 8)) * NH + c0*8;
  const uint16_t* pb0 = whobf + (long)(Nb + r0) * NH + c0*8;
  const uint16_t* pb1 = whobf + (long)(Nb + r1) * NH + c0*8;
  int da0 = r0*4 + (c0 ^ (r0 & 3));
  int da1 = r1*4 + (c0 ^ (r1 & 3));

  u32x4 ra0 = *(const u32x4*)pa0;
  u32x4 ra1 = *(const u32x4*)pa1;
  u32x4 rb0 = *(const u32x4*)pb0;
  u32x4 rb1 = *(const u32x4*)pb1;

  f32x4 acc[4][4];
  #pragma unroll
  for (int i = 0; i < 4; ++i)
    #pragma unroll
    for (int j = 0; j < 4; ++j) acc[i][j] = (f32x4){0.f,0.f,0.f,0.f};

  for (int kt = 0; kt < 32; ++kt){
    ((u32x4*)As)[da0] = ra0;
    ((u32x4*)As)[da1] = ra1;
    ((u32x4*)Bs)[da0] = rb0;
    ((u32x4*)Bs)[da1] = rb1;
    __syncthreads();
    if (kt != 31){
      int off = (kt + 1) * 32;
      ra0 = *(const u32x4*)(pa0 + off);
      ra1 = *(const u32x4*)(pa1 + off);
      rb0 = *(const u32x4*)(pb0 + off);
      rb1 = *(const u32x4*)(pb1 + off);
    }
    bf16x8 af[4], bg[4];
    #pragma unroll
    for (int i = 0; i < 4; ++i){
      int r  = wm*64 + i*16 + lr;
      int rb = wn*64 + i*16 + lr;
      af[i] = *(const bf16x8*)&((const u32x4*)As)[r*4  + (lk ^ (r  & 3))];
      bg[i] = *(const bf16x8*)&((const u32x4*)Bs)[rb*4 + (lk ^ (rb & 3))];
    }
    #pragma unroll
    for (int i = 0; i < 4; ++i)
      #pragma unroll
      for (int j = 0; j < 4; ++j)
        acc[i][j] = __builtin_amdgcn_mfma_f32_16x16x32_bf16(af[i], bg[j], acc[i][j], 0, 0, 0);
    __syncthreads();
  }

  #pragma unroll
  for (int j = 0; j < 4; ++j){
    int col = Nb + wn*64 + j*16 + lr;
    float bias = whob[col];
    #pragma unroll
    for (int i = 0; i < 4; ++i){
      #pragma unroll
      for (int r = 0; r < 4; ++r){
        int row = Mb + wm*64 + i*16 + lk*4 + r;
        out[(long)row * NV + col] = acc[i][j][r] + bias;
      }
    }
  }
}

extern "C" void kernel_launch(void* const* d_in, const int* in_sizes, int n_in,
                              void* d_out, int out_size, void* d_ws, size_t ws_size,
                              hipStream_t stream){
  (void)in_sizes; (void)n_in; (void)out_size;
  if (ws_size < (size_t)WS_NEED) return;   // insufficient scratch -> fail loudly (poison stays)

  const int*   ids    = (const int*)  d_in[0];
  const float* hidden = (const float*)d_in[1];
  const float* table  = (const float*)d_in[2];
  const float* wxh    = (const float*)d_in[3];
  const float* bxh    = (const float*)d_in[4];
  const float* whh    = (const float*)d_in[5];
  const float* who    = (const float*)d_in[6];
  const float* whob   = (const float*)d_in[7];

  char* ws = (char*)d_ws;
  float*    xp     = (float*)   (ws + WS_XP);
  uint16_t* hchain = (uint16_t*)(ws + WS_HCH);
  uint16_t* whobf  = (uint16_t*)(ws + WS_WHO);
  uint32_t* flags  = (uint32_t*)(ws + WS_FLAGS);
  float* out    = (float*)d_out;
  float* hfinal = out + (long)NB * NS * NV;   // 131,072,000

  k_init  <<<64,    256, 0, stream>>>(hidden, hchain, flags);
  k_cvt   <<<16000, 256, 0, stream>>>(who, (uint32_t*)whobf);
  k_xproj <<<1024,  256, 0, stream>>>(ids, table, wxh, bxh, xp);
  k_rnn   <<<64,    64,  0, stream>>>(whh, xp, hchain, flags, hfinal);
  k_logits<<<8000,  256, 0, stream>>>(hchain, whobf, whob, out);
}

// Round 4
// 1499.259 us; speedup vs baseline: 1.4229x; 1.0688x over previous
//
#include <hip/hip_runtime.h>
#include <stdint.h>

#define NB 16
#define NS 256
#define NV 32000
#define NE 512
#define NH 1024
#define PAD_IDX 3

// workspace byte offsets
#define WS_XP    0L                 // f32 [4096][1024]   16,777,216 B
#define WS_HCH   16777216L          // bf16 [257][16][1024] 8,421,376 B
#define WS_WHO   25198592L          // bf16 [32000][1024] 65,536,000 B
#define WS_NEED  90734592L

typedef __attribute__((ext_vector_type(8))) short bf16x8;
typedef __attribute__((ext_vector_type(4))) float f32x4;
typedef __attribute__((ext_vector_type(4))) uint32_t u32x4;

__device__ __forceinline__ uint16_t f2bf(float f){
  union { float f; uint32_t u; } v; v.f = f;
  return (uint16_t)((v.u + 0x7fffu + ((v.u >> 16) & 1u)) >> 16);  // RNE
}

__device__ __forceinline__ bf16x8 pack8(float4 a, float4 b){
  bf16x8 r;
  r[0]=(short)f2bf(a.x); r[1]=(short)f2bf(a.y); r[2]=(short)f2bf(a.z); r[3]=(short)f2bf(a.w);
  r[4]=(short)f2bf(b.x); r[5]=(short)f2bf(b.y); r[6]=(short)f2bf(b.z); r[7]=(short)f2bf(b.w);
  return r;
}

// coherent (device-scope) 16B load: bypasses L1/L2, reads the coherence point
__device__ __forceinline__ u32x4 load_coh16(const void* p){
  u32x4 r;
  asm volatile("global_load_dwordx4 %0, %1, off sc0 sc1" : "=v"(r) : "v"(p) : "memory");
  return r;
}
// coherent write-through 8B store
__device__ __forceinline__ void store_coh8(void* p, uint64_t v){
  asm volatile("global_store_dwordx2 %0, %1, off sc0 sc1" :: "v"(p), "v"(v) : "memory");
}

__device__ __forceinline__ u32x4 umax4(u32x4 a, u32x4 b){
  u32x4 r;
  r[0] = a[0] > b[0] ? a[0] : b[0];
  r[1] = a[1] > b[1] ? a[1] : b[1];
  r[2] = a[2] > b[2] ? a[2] : b[2];
  r[3] = a[3] > b[3] ? a[3] : b[3];
  return r;
}

// clamped fast tanh: (e^{2x}-1)/(e^{2x}+1) via exp2; abs err ~1e-5, never NaN/inf
__device__ __forceinline__ float tanh_fast(float x){
  x = fminf(fmaxf(x, -10.f), 10.f);
  float t = __builtin_amdgcn_exp2f(x * 2.885390081777927f);  // 2*log2(e)
  return (t - 1.0f) * __builtin_amdgcn_rcpf(t + 1.0f);
}

// ---- K0: sentinel-fill hchain slots 1..256 (bf16 NaN 0xFFFF), hidden -> slot 0
__global__ void k_init(const float* __restrict__ hidden, uint16_t* __restrict__ hch){
  long idx = (long)blockIdx.x * 256 + threadIdx.x;   // grid 2048*256 = 524,288
  ((u32x4*)(hch + (long)NB * NH))[idx] = (u32x4){~0u, ~0u, ~0u, ~0u};
  if (idx < NB * NH) hch[idx] = f2bf(hidden[idx]);
}

// ---- K1: Who_w f32 -> bf16 (row-major [32000][1024])
__global__ void k_cvt(const float* __restrict__ src, uint32_t* __restrict__ dst){
  long idx = (long)blockIdx.x * 256 + threadIdx.x;  // 4,096,000 threads, 8 f32 each
  const float4* p = (const float4*)src;
  float4 a = p[idx*2], b = p[idx*2+1];
  u32x4 d;
  d[0] = (uint32_t)f2bf(a.x) | ((uint32_t)f2bf(a.y) << 16);
  d[1] = (uint32_t)f2bf(a.z) | ((uint32_t)f2bf(a.w) << 16);
  d[2] = (uint32_t)f2bf(b.x) | ((uint32_t)f2bf(b.y) << 16);
  d[3] = (uint32_t)f2bf(b.z) | ((uint32_t)f2bf(b.w) << 16);
  ((u32x4*)dst)[idx] = d;
}

// ---- K2: xp[m][n] = sum_k emb(ids[m])[k] * Wxh[n][k] + b[n]   (m=(b,s), bf16 MFMA)
__global__ __launch_bounds__(256) void k_xproj(
    const int* __restrict__ ids, const float* __restrict__ tab,
    const float* __restrict__ wxh, const float* __restrict__ bxh,
    float* __restrict__ xp){
  int bid = blockIdx.x;                 // 64 M-tiles x 16 N-tiles
  int tm = bid & 63, tn = bid >> 6;
  int Mb = tm * 64, Nb = tn * 64;
  int tid = threadIdx.x;
  int w = tid >> 6, l = tid & 63;
  int lr = l & 15, lk = l >> 4;

  int m = Mb + w*16 + lr;
  int id = ids[m];
  const float* arow = tab + (long)id * NE;
  bool pad = (id == PAD_IDX);

  f32x4 acc[4];
  #pragma unroll
  for (int j = 0; j < 4; ++j) acc[j] = (f32x4){0.f,0.f,0.f,0.f};

  for (int k0 = 0; k0 < NE; k0 += 32){
    int k = k0 + lk*8;
    bf16x8 af = (bf16x8){0,0,0,0,0,0,0,0};
    if (!pad){
      float4 a = *(const float4*)(arow + k);
      float4 b = *(const float4*)(arow + k + 4);
      af = pack8(a, b);
    }
    #pragma unroll
    for (int j = 0; j < 4; ++j){
      const float* brow = wxh + (long)(Nb + j*16 + lr) * NE + k;
      float4 x = *(const float4*)brow;
      float4 y = *(const float4*)(brow + 4);
      bf16x8 bf_ = pack8(x, y);
      acc[j] = __builtin_amdgcn_mfma_f32_16x16x32_bf16(af, bf_, acc[j], 0, 0, 0);
    }
  }
  #pragma unroll
  for (int j = 0; j < 4; ++j){
    int n = Nb + j*16 + lr;
    float bias = bxh[n];
    #pragma unroll
    for (int r = 0; r < 4; ++r){
      int row = Mb + w*16 + lk*4 + r;
      xp[(long)row * NH + n] = acc[j][r] + bias;
    }
  }
}

// ---- K3: persistent recurrence, sentinel-poll protocol (no flags, no acks).
// 64 blocks x 1 wave; block owns 16 hidden cols. Consumers poll h_t directly:
// issue 32 coherent fragment loads, vmcnt(0), sched_barrier(0)  <-- REQUIRED:
// without it hipcc schedules the register-only umax check before the loads
// retire (rule #18 hazard) and the check passes on junk. Then umax-reduce vs
// the 0xFFFFFFFF sentinel, retry until all written — the passing iteration's
// registers feed the MFMA directly. Producers fire-and-forget write-through.
__global__ __launch_bounds__(64) void k_rnn(
    const float* __restrict__ whh, const float* __restrict__ xp,
    uint16_t* __restrict__ hch, float* __restrict__ hfin){
  __shared__ __align__(16) uint16_t whh_s[16*1024];  // bf16, 16B-chunk xor-swizzled
  __shared__ __align__(16) uint16_t hs2[16*16];      // output transpose buffer
  const int blk = blockIdx.x;     // 0..63
  const int l   = threadIdx.x;    // 0..63
  const int j0  = blk * 16;
  const int lr = l & 15, lk = l >> 4;

  // stage Whh rows [j0, j0+16) as bf16, swizzle chunk c -> c^(row&7)
  for (int it = 0; it < 32; ++it){
    int chunk = it*64 + l;        // 0..2047 = row*128 + c
    int row = chunk >> 7, c = chunk & 127;
    const float* s0 = whh + (long)(j0 + row) * NH + c*8;
    float4 a = *(const float4*)s0;
    float4 b = *(const float4*)(s0 + 4);
    u32x4 d;
    d[0] = (uint32_t)f2bf(a.x) | ((uint32_t)f2bf(a.y) << 16);
    d[1] = (uint32_t)f2bf(a.z) | ((uint32_t)f2bf(a.w) << 16);
    d[2] = (uint32_t)f2bf(b.x) | ((uint32_t)f2bf(b.y) << 16);
    d[3] = (uint32_t)f2bf(b.z) | ((uint32_t)f2bf(b.w) << 16);
    ((u32x4*)whh_s)[row*128 + (c ^ (row & 7))] = d;
  }
  __syncthreads();

  // prefetch xp for t=0 (normal cached loads)
  float xpreg[4];
  #pragma unroll
  for (int r = 0; r < 4; ++r){
    int b = lk*4 + r;
    xpreg[r] = xp[((long)b * NS + 0) * NH + j0 + lr];
  }

  const char* hbase = (const char*)hch;
  for (int t = 0; t < NS; ++t){
    // poll-load this lane's A-fragments: h[batch=lr][k = kk*32 + lk*8 .. +7]
    const char* hsrc = hbase + (long)t * NB * NH * 2 + lr * 2048 + lk * 16;
    u32x4 hfrag[32];
    while (true){
      #pragma unroll
      for (int kk = 0; kk < 32; ++kk)
        hfrag[kk] = load_coh16(hsrc + kk * 64);
      asm volatile("s_waitcnt vmcnt(0)" ::: "memory");
      __builtin_amdgcn_sched_barrier(0);   // pin the check AFTER the waitcnt
      u32x4 m4 = hfrag[0];
      #pragma unroll
      for (int kk = 1; kk < 32; ++kk) m4 = umax4(m4, hfrag[kk]);
      uint32_t m01 = m4[0] > m4[1] ? m4[0] : m4[1];
      uint32_t m23 = m4[2] > m4[3] ? m4[2] : m4[3];
      uint32_t m = m01 > m23 ? m01 : m23;
      if (__all(m != 0xFFFFFFFFu)) break;      // sentinel gone on all lanes
    }
    __builtin_amdgcn_sched_barrier(0);

    f32x4 a0 = (f32x4){0.f,0.f,0.f,0.f}, a1 = a0, a2 = a0, a3 = a0;
    #pragma unroll
    for (int kk = 0; kk < 32; kk += 4){
      int c0 = kk*4 + lk;
      bf16x8 b0 = *(const bf16x8*)&((const u32x4*)whh_s)[lr*128 + ( c0      ^ (lr & 7))];
      bf16x8 b1 = *(const bf16x8*)&((const u32x4*)whh_s)[lr*128 + ((c0 + 4) ^ (lr & 7))];
      bf16x8 b2 = *(const bf16x8*)&((const u32x4*)whh_s)[lr*128 + ((c0 + 8) ^ (lr & 7))];
      bf16x8 b3 = *(const bf16x8*)&((const u32x4*)whh_s)[lr*128 + ((c0 +12) ^ (lr & 7))];
      a0 = __builtin_amdgcn_mfma_f32_16x16x32_bf16(*(const bf16x8*)&hfrag[kk  ], b0, a0, 0, 0, 0);
      a1 = __builtin_amdgcn_mfma_f32_16x16x32_bf16(*(const bf16x8*)&hfrag[kk+1], b1, a1, 0, 0, 0);
      a2 = __builtin_amdgcn_mfma_f32_16x16x32_bf16(*(const bf16x8*)&hfrag[kk+2], b2, a2, 0, 0, 0);
      a3 = __builtin_amdgcn_mfma_f32_16x16x32_bf16(*(const bf16x8*)&hfrag[kk+3], b3, a3, 0, 0, 0);
    }
    f32x4 acc = (a0 + a1) + (a2 + a3);

    // tanh + transpose through tiny LDS buffer (C/D: row=(l>>4)*4+r, col=l&15)
    #pragma unroll
    for (int r = 0; r < 4; ++r){
      int b = lk*4 + r;
      float hv = tanh_fast(xpreg[r] + acc[r]);
      hs2[b*16 + lr] = f2bf(hv);
      if (t == NS-1) hfin[b*NH + j0 + lr] = hv;
    }
    __syncthreads();

    // coalesced write-through store (fire-and-forget): lane l -> row l>>2, 4 bf16
    {
      int rb = l >> 2, cc = l & 3;
      uint32_t w0 = *(const uint32_t*)&hs2[rb*16 + cc*4];
      uint32_t w1 = *(const uint32_t*)&hs2[rb*16 + cc*4 + 2];
      char* dst = (char*)hch + (long)(t+1) * NB * NH * 2 + rb * 2048 + j0*2 + cc*8;
      store_coh8(dst, ((uint64_t)w1 << 32) | (uint64_t)w0);
    }

    // prefetch xp for t+1; completes while next poll runs
    if (t + 1 < NS){
      #pragma unroll
      for (int r = 0; r < 4; ++r){
        int b = lk*4 + r;
        xpreg[r] = xp[((long)b * NS + (t+1)) * NH + j0 + lr];
      }
    }
    __syncthreads();   // protect hs2 reuse (1 wave, cheap)
  }
}

// ---- K4: logits = h_all * Who^T + b. 128x128 tile, BK=32, 4 waves 2x2, bf16 MFMA.
__global__ __launch_bounds__(256) void k_logits(
    const uint16_t* __restrict__ hch, const uint16_t* __restrict__ whobf,
    const float* __restrict__ whob, float* __restrict__ out){
  __shared__ __align__(16) uint16_t As[128*32];
  __shared__ __align__(16) uint16_t Bs[128*32];
  int bid = blockIdx.x;                      // 8000 = 32 Mtiles * 250 Ntiles
  int swz = (bid & 7) * 1000 + (bid >> 3);   // XCD-aware (8000 % 8 == 0, bijective)
  int tm = swz & 31, tn = swz >> 5;
  int Mb = tm * 128, Nb = tn * 128;
  int tid = threadIdx.x;
  int w = tid >> 6, l = tid & 63;
  int wm = w >> 1, wn = w & 1;
  int lr = l & 15, lk = l >> 4;

  // staging: thread owns chunks (r0,c0) and (r0+64,c0) of both tiles
  int r0 = tid >> 2, c0 = tid & 3;
  int r1 = r0 + 64;
  int m0 = Mb + r0, m1 = Mb + r1;            // A row -> (b=m>>8, s=m&255), slot s+1
  const uint16_t* pa0 = hch + ((long)((m0 & 255) + 1) * 16 + (m0 >> 8)) * NH + c0*8;
  const uint16_t* pa1 = hch + ((long)((m1 & 255) + 1) * 16 + (m1 >> 8)) * NH + c0*8;
  const uint16_t* pb0 = whobf + (long)(Nb + r0) * NH + c0*8;
  const uint16_t* pb1 = whobf + (long)(Nb + r1) * NH + c0*8;
  int da0 = r0*4 + (c0 ^ (r0 & 3));
  int da1 = r1*4 + (c0 ^ (r1 & 3));

  u32x4 ra0 = *(const u32x4*)pa0;
  u32x4 ra1 = *(const u32x4*)pa1;
  u32x4 rb0 = *(const u32x4*)pb0;
  u32x4 rb1 = *(const u32x4*)pb1;

  f32x4 acc[4][4];
  #pragma unroll
  for (int i = 0; i < 4; ++i)
    #pragma unroll
    for (int j = 0; j < 4; ++j) acc[i][j] = (f32x4){0.f,0.f,0.f,0.f};

  for (int kt = 0; kt < 32; ++kt){
    ((u32x4*)As)[da0] = ra0;
    ((u32x4*)As)[da1] = ra1;
    ((u32x4*)Bs)[da0] = rb0;
    ((u32x4*)Bs)[da1] = rb1;
    __syncthreads();
    if (kt != 31){
      int off = (kt + 1) * 32;
      ra0 = *(const u32x4*)(pa0 + off);
      ra1 = *(const u32x4*)(pa1 + off);
      rb0 = *(const u32x4*)(pb0 + off);
      rb1 = *(const u32x4*)(pb1 + off);
    }
    bf16x8 af[4], bg[4];
    #pragma unroll
    for (int i = 0; i < 4; ++i){
      int r  = wm*64 + i*16 + lr;
      int rb = wn*64 + i*16 + lr;
      af[i] = *(const bf16x8*)&((const u32x4*)As)[r*4  + (lk ^ (r  & 3))];
      bg[i] = *(const bf16x8*)&((const u32x4*)Bs)[rb*4 + (lk ^ (rb & 3))];
    }
    #pragma unroll
    for (int i = 0; i < 4; ++i)
      #pragma unroll
      for (int j = 0; j < 4; ++j)
        acc[i][j] = __builtin_amdgcn_mfma_f32_16x16x32_bf16(af[i], bg[j], acc[i][j], 0, 0, 0);
    __syncthreads();
  }

  #pragma unroll
  for (int j = 0; j < 4; ++j){
    int col = Nb + wn*64 + j*16 + lr;
    float bias = whob[col];
    #pragma unroll
    for (int i = 0; i < 4; ++i){
      #pragma unroll
      for (int r = 0; r < 4; ++r){
        int row = Mb + wm*64 + i*16 + lk*4 + r;
        out[(long)row * NV + col] = acc[i][j][r] + bias;
      }
    }
  }
}

extern "C" void kernel_launch(void* const* d_in, const int* in_sizes, int n_in,
                              void* d_out, int out_size, void* d_ws, size_t ws_size,
                              hipStream_t stream){
  (void)in_sizes; (void)n_in; (void)out_size;
  if (ws_size < (size_t)WS_NEED) return;   // insufficient scratch -> fail loudly (poison stays)

  const int*   ids    = (const int*)  d_in[0];
  const float* hidden = (const float*)d_in[1];
  const float* table  = (const float*)d_in[2];
  const float* wxh    = (const float*)d_in[3];
  const float* bxh    = (const float*)d_in[4];
  const float* whh    = (const float*)d_in[5];
  const float* who    = (const float*)d_in[6];
  const float* whob   = (const float*)d_in[7];

  char* ws = (char*)d_ws;
  float*    xp     = (float*)   (ws + WS_XP);
  uint16_t* hchain = (uint16_t*)(ws + WS_HCH);
  uint16_t* whobf  = (uint16_t*)(ws + WS_WHO);
  float* out    = (float*)d_out;
  float* hfinal = out + (long)NB * NS * NV;   // 131,072,000

  k_init  <<<2048,  256, 0, stream>>>(hidden, hchain);
  k_cvt   <<<16000, 256, 0, stream>>>(who, (uint32_t*)whobf);
  k_xproj <<<1024,  256, 0, stream>>>(ids, table, wxh, bxh, xp);
  k_rnn   <<<64,    64,  0, stream>>>(whh, xp, hchain, hfinal);
  k_logits<<<8000,  256, 0, stream>>>(hchain, whobf, whob, out);
}

// Round 5
// 1456.840 us; speedup vs baseline: 1.4644x; 1.0291x over previous
//
#include <hip/hip_runtime.h>
#include <stdint.h>

#define NB 16
#define NS 256
#define NV 32000
#define NE 512
#define NH 1024
#define PAD_IDX 3

// workspace byte offsets
#define WS_XP    0L                 // f32 [4096][1024]   16,777,216 B
#define WS_HCH   16777216L          // bf16 [257][16][1024] 8,421,376 B
#define WS_WHO   25198592L          // bf16 [32000][1024] 65,536,000 B
#define WS_NEED  90734592L

typedef __attribute__((ext_vector_type(8))) short bf16x8;
typedef __attribute__((ext_vector_type(4))) float f32x4;
typedef __attribute__((ext_vector_type(4))) uint32_t u32x4;

__device__ __forceinline__ uint16_t f2bf(float f){
  union { float f; uint32_t u; } v; v.f = f;
  return (uint16_t)((v.u + 0x7fffu + ((v.u >> 16) & 1u)) >> 16);  // RNE
}

__device__ __forceinline__ bf16x8 pack8(float4 a, float4 b){
  bf16x8 r;
  r[0]=(short)f2bf(a.x); r[1]=(short)f2bf(a.y); r[2]=(short)f2bf(a.z); r[3]=(short)f2bf(a.w);
  r[4]=(short)f2bf(b.x); r[5]=(short)f2bf(b.y); r[6]=(short)f2bf(b.z); r[7]=(short)f2bf(b.w);
  return r;
}

// coherent (device-scope) 16B load: bypasses L1/L2, reads the coherence point
__device__ __forceinline__ u32x4 load_coh16(const void* p){
  u32x4 r;
  asm volatile("global_load_dwordx4 %0, %1, off sc0 sc1" : "=v"(r) : "v"(p) : "memory");
  return r;
}
__device__ __forceinline__ uint64_t load_coh8(const void* p){
  uint64_t r;
  asm volatile("global_load_dwordx2 %0, %1, off sc0 sc1" : "=v"(r) : "v"(p) : "memory");
  return r;
}
// coherent write-through 8B store
__device__ __forceinline__ void store_coh8(void* p, uint64_t v){
  asm volatile("global_store_dwordx2 %0, %1, off sc0 sc1" :: "v"(p), "v"(v) : "memory");
}

__device__ __forceinline__ u32x4 umax4(u32x4 a, u32x4 b){
  u32x4 r;
  r[0] = a[0] > b[0] ? a[0] : b[0];
  r[1] = a[1] > b[1] ? a[1] : b[1];
  r[2] = a[2] > b[2] ? a[2] : b[2];
  r[3] = a[3] > b[3] ? a[3] : b[3];
  return r;
}

// clamped fast tanh: (e^{2x}-1)/(e^{2x}+1) via exp2; abs err ~1e-5, never NaN/inf
__device__ __forceinline__ float tanh_fast(float x){
  x = fminf(fmaxf(x, -10.f), 10.f);
  float t = __builtin_amdgcn_exp2f(x * 2.885390081777927f);  // 2*log2(e)
  return (t - 1.0f) * __builtin_amdgcn_rcpf(t + 1.0f);
}

// ---- K0: sentinel-fill hchain slots 1..256 (bf16 NaN 0xFFFF), hidden -> slot 0
__global__ void k_init(const float* __restrict__ hidden, uint16_t* __restrict__ hch){
  long idx = (long)blockIdx.x * 256 + threadIdx.x;   // grid 2048*256 = 524,288
  ((u32x4*)(hch + (long)NB * NH))[idx] = (u32x4){~0u, ~0u, ~0u, ~0u};
  if (idx < NB * NH) hch[idx] = f2bf(hidden[idx]);
}

// ---- K1: Who_w f32 -> bf16 (row-major [32000][1024])
__global__ void k_cvt(const float* __restrict__ src, uint32_t* __restrict__ dst){
  long idx = (long)blockIdx.x * 256 + threadIdx.x;  // 4,096,000 threads, 8 f32 each
  const float4* p = (const float4*)src;
  float4 a = p[idx*2], b = p[idx*2+1];
  u32x4 d;
  d[0] = (uint32_t)f2bf(a.x) | ((uint32_t)f2bf(a.y) << 16);
  d[1] = (uint32_t)f2bf(a.z) | ((uint32_t)f2bf(a.w) << 16);
  d[2] = (uint32_t)f2bf(b.x) | ((uint32_t)f2bf(b.y) << 16);
  d[3] = (uint32_t)f2bf(b.z) | ((uint32_t)f2bf(b.w) << 16);
  ((u32x4*)dst)[idx] = d;
}

// ---- K2: xp[m][n] = sum_k emb(ids[m])[k] * Wxh[n][k] + b[n]   (m=(b,s), bf16 MFMA)
__global__ __launch_bounds__(256) void k_xproj(
    const int* __restrict__ ids, const float* __restrict__ tab,
    const float* __restrict__ wxh, const float* __restrict__ bxh,
    float* __restrict__ xp){
  int bid = blockIdx.x;                 // 64 M-tiles x 16 N-tiles
  int tm = bid & 63, tn = bid >> 6;
  int Mb = tm * 64, Nb = tn * 64;
  int tid = threadIdx.x;
  int w = tid >> 6, l = tid & 63;
  int lr = l & 15, lk = l >> 4;

  int m = Mb + w*16 + lr;
  int id = ids[m];
  const float* arow = tab + (long)id * NE;
  bool pad = (id == PAD_IDX);

  f32x4 acc[4];
  #pragma unroll
  for (int j = 0; j < 4; ++j) acc[j] = (f32x4){0.f,0.f,0.f,0.f};

  for (int k0 = 0; k0 < NE; k0 += 32){
    int k = k0 + lk*8;
    bf16x8 af = (bf16x8){0,0,0,0,0,0,0,0};
    if (!pad){
      float4 a = *(const float4*)(arow + k);
      float4 b = *(const float4*)(arow + k + 4);
      af = pack8(a, b);
    }
    #pragma unroll
    for (int j = 0; j < 4; ++j){
      const float* brow = wxh + (long)(Nb + j*16 + lr) * NE + k;
      float4 x = *(const float4*)brow;
      float4 y = *(const float4*)(brow + 4);
      bf16x8 bf_ = pack8(x, y);
      acc[j] = __builtin_amdgcn_mfma_f32_16x16x32_bf16(af, bf_, acc[j], 0, 0, 0);
    }
  }
  #pragma unroll
  for (int j = 0; j < 4; ++j){
    int n = Nb + j*16 + lr;
    float bias = bxh[n];
    #pragma unroll
    for (int r = 0; r < 4; ++r){
      int row = Mb + w*16 + lk*4 + r;
      xp[(long)row * NH + n] = acc[j][r] + bias;
    }
  }
}

// ---- K3 fused: blocks 0..63 = persistent RNN (wave 0 only); blocks 64..8063 =
// logits tiles, s-ordered, each gated on visibility of its highest needed h slot.
// RNN protocol gives slot-monotonicity at L3: a producer stores slot t+1 only
// after its coherent poll of the FULL slot t passed, so "any slot-hs datum
// visible => all slots < hs fully visible". Gate checks the hs row directly.
__global__ __launch_bounds__(256) void k_fused(
    const float* __restrict__ whh, const float* __restrict__ xp,
    uint16_t* __restrict__ hch, const uint16_t* __restrict__ whobf,
    const float* __restrict__ whob, float* __restrict__ out,
    float* __restrict__ hfin){
  __shared__ __align__(16) char smem[33*1024 + 1024];
  const int bid = blockIdx.x;
  const int tid = threadIdx.x;

  if (bid < 64){
    // ================= RNN path (wave 0 only) =================
    if (tid >= 64) return;
    uint16_t* whh_s = (uint16_t*)smem;                 // 32 KB, xor-swizzled
    uint16_t* hs2   = (uint16_t*)(smem + 33*1024);     // [2][256] double buffer
    const int blk = bid;
    const int l   = tid;
    const int j0  = blk * 16;
    const int lr = l & 15, lk = l >> 4;

    for (int it = 0; it < 32; ++it){
      int chunk = it*64 + l;        // 0..2047 = row*128 + c
      int row = chunk >> 7, c = chunk & 127;
      const float* s0 = whh + (long)(j0 + row) * NH + c*8;
      float4 a = *(const float4*)s0;
      float4 b = *(const float4*)(s0 + 4);
      u32x4 d;
      d[0] = (uint32_t)f2bf(a.x) | ((uint32_t)f2bf(a.y) << 16);
      d[1] = (uint32_t)f2bf(a.z) | ((uint32_t)f2bf(a.w) << 16);
      d[2] = (uint32_t)f2bf(b.x) | ((uint32_t)f2bf(b.y) << 16);
      d[3] = (uint32_t)f2bf(b.z) | ((uint32_t)f2bf(b.w) << 16);
      ((u32x4*)whh_s)[row*128 + (c ^ (row & 7))] = d;
    }
    asm volatile("s_waitcnt lgkmcnt(0)" ::: "memory");   // single-wave: no barrier
    __builtin_amdgcn_sched_barrier(0);

    float xpreg[4];
    #pragma unroll
    for (int r = 0; r < 4; ++r){
      int b = lk*4 + r;
      xpreg[r] = xp[((long)b * NS + 0) * NH + j0 + lr];
    }

    const char* hbase = (const char*)hch;
    for (int t = 0; t < NS; ++t){
      const char* hsrc = hbase + (long)t * NB * NH * 2 + lr * 2048 + lk * 16;
      u32x4 hfrag[32];
      while (true){
        #pragma unroll
        for (int kk = 0; kk < 32; ++kk)
          hfrag[kk] = load_coh16(hsrc + kk * 64);
        asm volatile("s_waitcnt vmcnt(0)" ::: "memory");
        __builtin_amdgcn_sched_barrier(0);   // pin check AFTER the waitcnt (rule #18)
        u32x4 m4 = hfrag[0];
        #pragma unroll
        for (int kk = 1; kk < 32; ++kk) m4 = umax4(m4, hfrag[kk]);
        uint32_t m01 = m4[0] > m4[1] ? m4[0] : m4[1];
        uint32_t m23 = m4[2] > m4[3] ? m4[2] : m4[3];
        uint32_t m = m01 > m23 ? m01 : m23;
        if (__all(m != 0xFFFFFFFFu)) break;
      }
      __builtin_amdgcn_sched_barrier(0);

      f32x4 a0 = (f32x4){0.f,0.f,0.f,0.f}, a1 = a0, a2 = a0, a3 = a0;
      #pragma unroll
      for (int kk = 0; kk < 32; kk += 4){
        int c0 = kk*4 + lk;
        bf16x8 b0 = *(const bf16x8*)&((const u32x4*)whh_s)[lr*128 + ( c0      ^ (lr & 7))];
        bf16x8 b1 = *(const bf16x8*)&((const u32x4*)whh_s)[lr*128 + ((c0 + 4) ^ (lr & 7))];
        bf16x8 b2 = *(const bf16x8*)&((const u32x4*)whh_s)[lr*128 + ((c0 + 8) ^ (lr & 7))];
        bf16x8 b3 = *(const bf16x8*)&((const u32x4*)whh_s)[lr*128 + ((c0 +12) ^ (lr & 7))];
        a0 = __builtin_amdgcn_mfma_f32_16x16x32_bf16(*(const bf16x8*)&hfrag[kk  ], b0, a0, 0, 0, 0);
        a1 = __builtin_amdgcn_mfma_f32_16x16x32_bf16(*(const bf16x8*)&hfrag[kk+1], b1, a1, 0, 0, 0);
        a2 = __builtin_amdgcn_mfma_f32_16x16x32_bf16(*(const bf16x8*)&hfrag[kk+2], b2, a2, 0, 0, 0);
        a3 = __builtin_amdgcn_mfma_f32_16x16x32_bf16(*(const bf16x8*)&hfrag[kk+3], b3, a3, 0, 0, 0);
      }
      f32x4 acc = (a0 + a1) + (a2 + a3);

      uint16_t* hb = hs2 + (t & 1) * 256;   // double buffer kills WAR across steps
      #pragma unroll
      for (int r = 0; r < 4; ++r){
        int b = lk*4 + r;
        float hv = tanh_fast(xpreg[r] + acc[r]);
        hb[b*16 + lr] = f2bf(hv);
        if (t == NS-1) hfin[b*NH + j0 + lr] = hv;
      }
      asm volatile("s_waitcnt lgkmcnt(0)" ::: "memory");
      __builtin_amdgcn_sched_barrier(0);

      {
        int rb = l >> 2, cc = l & 3;
        uint32_t w0 = *(const uint32_t*)&hb[rb*16 + cc*4];
        uint32_t w1 = *(const uint32_t*)&hb[rb*16 + cc*4 + 2];
        char* dst = (char*)hch + (long)(t+1) * NB * NH * 2 + rb * 2048 + j0*2 + cc*8;
        store_coh8(dst, ((uint64_t)w1 << 32) | (uint64_t)w0);
      }

      if (t + 1 < NS){
        #pragma unroll
        for (int r = 0; r < 4; ++r){
          int b = lk*4 + r;
          xpreg[r] = xp[((long)b * NS + (t+1)) * NH + j0 + lr];
        }
      }
    }
    return;
  }

  // ================= logits path =================
  uint16_t* As = (uint16_t*)smem;          // 8 KB
  uint16_t* Bs = (uint16_t*)(smem + 8192); // 8 KB
  int w = bid - 64;                        // 0..7999, s-ascending halves
  int half = (w >= 4000) ? 1 : 0;
  int wp = w - half*4000;
  int sw = (wp & 7)*500 + (wp >> 3);       // XCD-contiguous chunks (bid%8 == wp%8)
  int tn = sw / 16, tmh = sw % 16;
  int tm = tmh*2 + half;                   // even tiles: slots<=128; odd: <=256
  int Mb = tm*128, Nb = tn*128;
  int bg = tm >> 1;                        // batch of this M-tile
  int hs = half ? 256 : 128;               // highest needed slot

  // visibility gate: full 1024-col row (slot hs, batch bg), 256 thr x 8B
  {
    const char* gp = (const char*)hch + ((long)hs*NB + bg)*NH*2 + tid*8;
    while (true){
      uint64_t v = load_coh8(gp);
      asm volatile("s_waitcnt vmcnt(0)" ::: "memory");
      __builtin_amdgcn_sched_barrier(0);
      int bad = (v == ~0ull);
      if (__syncthreads_count(bad) == 0) break;
      __builtin_amdgcn_s_sleep(8);
    }
  }

  int tt = tid;
  int wv = tt >> 6, l = tt & 63;
  int wm = wv >> 1, wn = wv & 1;
  int lr = l & 15, lk = l >> 4;

  int r0 = tt >> 2, c0 = tt & 3;
  int r1 = r0 + 64;
  int m0 = Mb + r0, m1 = Mb + r1;          // A row -> (b=m>>8, s=m&255), slot s+1
  const uint16_t* pa0 = hch + ((long)((m0 & 255) + 1) * 16 + (m0 >> 8)) * NH + c0*8;
  const uint16_t* pa1 = hch + ((long)((m1 & 255) + 1) * 16 + (m1 >> 8)) * NH + c0*8;
  const uint16_t* pb0 = whobf + (long)(Nb + r0) * NH + c0*8;
  const uint16_t* pb1 = whobf + (long)(Nb + r1) * NH + c0*8;
  int da0 = r0*4 + (c0 ^ (r0 & 3));
  int da1 = r1*4 + (c0 ^ (r1 & 3));

  u32x4 ra0 = *(const u32x4*)pa0;
  u32x4 ra1 = *(const u32x4*)pa1;
  u32x4 rb0 = *(const u32x4*)pb0;
  u32x4 rb1 = *(const u32x4*)pb1;

  f32x4 acc[4][4];
  #pragma unroll
  for (int i = 0; i < 4; ++i)
    #pragma unroll
    for (int j = 0; j < 4; ++j) acc[i][j] = (f32x4){0.f,0.f,0.f,0.f};

  for (int kt = 0; kt < 32; ++kt){
    ((u32x4*)As)[da0] = ra0;
    ((u32x4*)As)[da1] = ra1;
    ((u32x4*)Bs)[da0] = rb0;
    ((u32x4*)Bs)[da1] = rb1;
    __syncthreads();
    if (kt != 31){
      int off = (kt + 1) * 32;
      ra0 = *(const u32x4*)(pa0 + off);
      ra1 = *(const u32x4*)(pa1 + off);
      rb0 = *(const u32x4*)(pb0 + off);
      rb1 = *(const u32x4*)(pb1 + off);
    }
    bf16x8 af[4], bg_[4];
    #pragma unroll
    for (int i = 0; i < 4; ++i){
      int r  = wm*64 + i*16 + lr;
      int rb = wn*64 + i*16 + lr;
      af[i]  = *(const bf16x8*)&((const u32x4*)As)[r*4  + (lk ^ (r  & 3))];
      bg_[i] = *(const bf16x8*)&((const u32x4*)Bs)[rb*4 + (lk ^ (rb & 3))];
    }
    #pragma unroll
    for (int i = 0; i < 4; ++i)
      #pragma unroll
      for (int j = 0; j < 4; ++j)
        acc[i][j] = __builtin_amdgcn_mfma_f32_16x16x32_bf16(af[i], bg_[j], acc[i][j], 0, 0, 0);
    __syncthreads();
  }

  #pragma unroll
  for (int j = 0; j < 4; ++j){
    int col = Nb + wn*64 + j*16 + lr;
    float bias = whob[col];
    #pragma unroll
    for (int i = 0; i < 4; ++i){
      #pragma unroll
      for (int r = 0; r < 4; ++r){
        int row = Mb + wm*64 + i*16 + lk*4 + r;
        out[(long)row * NV + col] = acc[i][j][r] + bias;
      }
    }
  }
}

extern "C" void kernel_launch(void* const* d_in, const int* in_sizes, int n_in,
                              void* d_out, int out_size, void* d_ws, size_t ws_size,
                              hipStream_t stream){
  (void)in_sizes; (void)n_in; (void)out_size;
  if (ws_size < (size_t)WS_NEED) return;   // insufficient scratch -> fail loudly (poison stays)

  const int*   ids    = (const int*)  d_in[0];
  const float* hidden = (const float*)d_in[1];
  const float* table  = (const float*)d_in[2];
  const float* wxh    = (const float*)d_in[3];
  const float* bxh    = (const float*)d_in[4];
  const float* whh    = (const float*)d_in[5];
  const float* who    = (const float*)d_in[6];
  const float* whob   = (const float*)d_in[7];

  char* ws = (char*)d_ws;
  float*    xp     = (float*)   (ws + WS_XP);
  uint16_t* hchain = (uint16_t*)(ws + WS_HCH);
  uint16_t* whobf  = (uint16_t*)(ws + WS_WHO);
  float* out    = (float*)d_out;
  float* hfinal = out + (long)NB * NS * NV;   // 131,072,000

  k_init <<<2048,  256, 0, stream>>>(hidden, hchain);
  k_cvt  <<<16000, 256, 0, stream>>>(who, (uint32_t*)whobf);
  k_xproj<<<1024,  256, 0, stream>>>(ids, table, wxh, bxh, xp);
  k_fused<<<8064,  256, 0, stream>>>(whh, xp, hchain, whobf, whob, out, hfinal);
}

// Round 6
// 1273.438 us; speedup vs baseline: 1.6753x; 1.1440x over previous
//
#include <hip/hip_runtime.h>
#include <stdint.h>

#define NB 16
#define NS 256
#define NV 32000
#define NE 512
#define NH 1024
#define PAD_IDX 3

// workspace byte offsets
#define WS_XP    0L                 // f32 [4096][1024]   16,777,216 B
#define WS_HCH   16777216L          // bf16 [257][16][1024] 8,421,376 B
#define WS_WHO   25198592L          // bf16 [32000][1024] 65,536,000 B
#define WS_FLG   90734592L          // u32 [257][64]          65,792 B
#define WS_NEED  90800384L

typedef __attribute__((ext_vector_type(8))) short bf16x8;
typedef __attribute__((ext_vector_type(4))) float f32x4;
typedef __attribute__((ext_vector_type(4))) uint32_t u32x4;

__device__ __forceinline__ uint16_t f2bf(float f){
  union { float f; uint32_t u; } v; v.f = f;
  return (uint16_t)((v.u + 0x7fffu + ((v.u >> 16) & 1u)) >> 16);  // RNE
}

__device__ __forceinline__ bf16x8 pack8(float4 a, float4 b){
  bf16x8 r;
  r[0]=(short)f2bf(a.x); r[1]=(short)f2bf(a.y); r[2]=(short)f2bf(a.z); r[3]=(short)f2bf(a.w);
  r[4]=(short)f2bf(b.x); r[5]=(short)f2bf(b.y); r[6]=(short)f2bf(b.z); r[7]=(short)f2bf(b.w);
  return r;
}

// coherent (device-scope) loads/stores: bypass L1/L2, hit the coherence point
__device__ __forceinline__ u32x4 load_coh16(const void* p){
  u32x4 r;
  asm volatile("global_load_dwordx4 %0, %1, off sc0 sc1" : "=v"(r) : "v"(p) : "memory");
  return r;
}
__device__ __forceinline__ uint32_t load_coh4(const void* p){
  uint32_t r;
  asm volatile("global_load_dword %0, %1, off sc0 sc1" : "=v"(r) : "v"(p) : "memory");
  return r;
}
__device__ __forceinline__ void store_coh8(void* p, uint64_t v){
  asm volatile("global_store_dwordx2 %0, %1, off sc0 sc1" :: "v"(p), "v"(v) : "memory");
}
__device__ __forceinline__ void store_coh4(void* p, uint32_t v){
  asm volatile("global_store_dword %0, %1, off sc0 sc1" :: "v"(p), "v"(v) : "memory");
}

__device__ __forceinline__ u32x4 umax4(u32x4 a, u32x4 b){
  u32x4 r;
  r[0] = a[0] > b[0] ? a[0] : b[0];
  r[1] = a[1] > b[1] ? a[1] : b[1];
  r[2] = a[2] > b[2] ? a[2] : b[2];
  r[3] = a[3] > b[3] ? a[3] : b[3];
  return r;
}

// clamped fast tanh: (e^{2x}-1)/(e^{2x}+1) via exp2; abs err ~1e-5, never NaN/inf
__device__ __forceinline__ float tanh_fast(float x){
  x = fminf(fmaxf(x, -10.f), 10.f);
  float t = __builtin_amdgcn_exp2f(x * 2.885390081777927f);  // 2*log2(e)
  return (t - 1.0f) * __builtin_amdgcn_rcpf(t + 1.0f);
}

// ---- K0: sentinel-fill hchain slots 1..256, hidden -> slot 0, zero done flags
__global__ void k_init(const float* __restrict__ hidden, uint16_t* __restrict__ hch,
                       uint32_t* __restrict__ done){
  long idx = (long)blockIdx.x * 256 + threadIdx.x;   // grid 2048*256 = 524,288
  ((u32x4*)(hch + (long)NB * NH))[idx] = (u32x4){~0u, ~0u, ~0u, ~0u};
  if (idx < NB * NH) hch[idx] = f2bf(hidden[idx]);
  if (idx < 257 * 64) done[idx] = 0u;
}

// ---- K1: Who_w f32 -> bf16 (row-major [32000][1024])
__global__ void k_cvt(const float* __restrict__ src, uint32_t* __restrict__ dst){
  long idx = (long)blockIdx.x * 256 + threadIdx.x;  // 4,096,000 threads, 8 f32 each
  const float4* p = (const float4*)src;
  float4 a = p[idx*2], b = p[idx*2+1];
  u32x4 d;
  d[0] = (uint32_t)f2bf(a.x) | ((uint32_t)f2bf(a.y) << 16);
  d[1] = (uint32_t)f2bf(a.z) | ((uint32_t)f2bf(a.w) << 16);
  d[2] = (uint32_t)f2bf(b.x) | ((uint32_t)f2bf(b.y) << 16);
  d[3] = (uint32_t)f2bf(b.z) | ((uint32_t)f2bf(b.w) << 16);
  ((u32x4*)dst)[idx] = d;
}

// ---- K2: xp[m][n] = sum_k emb(ids[m])[k] * Wxh[n][k] + b[n]   (m=(b,s), bf16 MFMA)
__global__ __launch_bounds__(256) void k_xproj(
    const int* __restrict__ ids, const float* __restrict__ tab,
    const float* __restrict__ wxh, const float* __restrict__ bxh,
    float* __restrict__ xp){
  int bid = blockIdx.x;                 // 64 M-tiles x 16 N-tiles
  int tm = bid & 63, tn = bid >> 6;
  int Mb = tm * 64, Nb = tn * 64;
  int tid = threadIdx.x;
  int w = tid >> 6, l = tid & 63;
  int lr = l & 15, lk = l >> 4;

  int m = Mb + w*16 + lr;
  int id = ids[m];
  const float* arow = tab + (long)id * NE;
  bool pad = (id == PAD_IDX);

  f32x4 acc[4];
  #pragma unroll
  for (int j = 0; j < 4; ++j) acc[j] = (f32x4){0.f,0.f,0.f,0.f};

  for (int k0 = 0; k0 < NE; k0 += 32){
    int k = k0 + lk*8;
    bf16x8 af = (bf16x8){0,0,0,0,0,0,0,0};
    if (!pad){
      float4 a = *(const float4*)(arow + k);
      float4 b = *(const float4*)(arow + k + 4);
      af = pack8(a, b);
    }
    #pragma unroll
    for (int j = 0; j < 4; ++j){
      const float* brow = wxh + (long)(Nb + j*16 + lr) * NE + k;
      float4 x = *(const float4*)brow;
      float4 y = *(const float4*)(brow + 4);
      bf16x8 bf_ = pack8(x, y);
      acc[j] = __builtin_amdgcn_mfma_f32_16x16x32_bf16(af, bf_, acc[j], 0, 0, 0);
    }
  }
  #pragma unroll
  for (int j = 0; j < 4; ++j){
    int n = Nb + j*16 + lr;
    float bias = bxh[n];
    #pragma unroll
    for (int r = 0; r < 4; ++r){
      int row = Mb + w*16 + lk*4 + r;
      xp[(long)row * NH + n] = acc[j][r] + bias;
    }
  }
}

// ---- K3 fused.
// Blocks 0..63: persistent RNN, 2 waves split-K (wave w owns K-half w). Whh
//   fragments live in REGISTERS (64 VGPR/wave); per step each wave sentinel-
//   polls its K-half of h_t (16 coherent 16B loads), MFMAs into a partial acc,
//   wave1 passes its partial through LDS, wave0 combines+tanh+stores slot t+1
//   (write-through) and sets done[t] flag (ack folded into next poll's vmcnt).
// Blocks 64..8063: logits tiles, s-major M (m = s*16+b), tile tm spans 8 steps,
//   gated on done[tm*8+8][0..63] (64B flag poll, s_sleep backoff).
__global__ __launch_bounds__(256, 2) void k_fused(
    const float* __restrict__ whh, const float* __restrict__ xp,
    uint16_t* __restrict__ hch, const uint16_t* __restrict__ whobf,
    const float* __restrict__ whob, uint32_t* __restrict__ done,
    float* __restrict__ out, float* __restrict__ hfin){
  __shared__ __align__(16) char smem[17*1024];
  const int bid = blockIdx.x;
  const int tid = threadIdx.x;

  if (bid < 64){
    // ================= RNN path (2 waves, split-K) =================
    if (tid >= 128) return;
    float*    accbuf = (float*)smem;                 // [2][64][4] f32, 2 KB
    uint16_t* hs2    = (uint16_t*)(smem + 2048);     // [2][256] bf16, 1 KB
    const int wv = tid >> 6;        // 0 or 1 (K-half)
    const int l  = tid & 63;
    const int j0 = bid * 16;
    const int lr = l & 15, lk = l >> 4;

    // Whh fragments for this wave's K-half -> registers (64 VGPR)
    bf16x8 bfrag[16];
    #pragma unroll
    for (int kk = 0; kk < 16; ++kk){
      const float* s0 = whh + (long)(j0 + lr) * NH + (wv*16 + kk)*32 + lk*8;
      float4 a = *(const float4*)s0;
      float4 b = *(const float4*)(s0 + 4);
      bfrag[kk] = pack8(a, b);
    }

    float xpreg[4];
    if (wv == 0){
      #pragma unroll
      for (int r = 0; r < 4; ++r)
        xpreg[r] = xp[((long)(lk*4 + r) * NS + 0) * NH + j0 + lr];
    }

    const char* hbase = (const char*)hch;
    for (int t = 0; t < NS; ++t){
      // poll this wave's K-half of slot t: h[batch=lr][k = (wv*16+kk)*32 + lk*8]
      const char* hsrc = hbase + (long)t * NB * NH * 2 + lr * 2048 + wv * 1024 + lk * 16;
      u32x4 hfrag[16];
      bool first = true;
      while (true){
        #pragma unroll
        for (int kk = 0; kk < 16; ++kk)
          hfrag[kk] = load_coh16(hsrc + kk * 64);
        asm volatile("s_waitcnt vmcnt(0)" ::: "memory");
        __builtin_amdgcn_sched_barrier(0);   // pin check AFTER waitcnt (rule #18)
        if (first){
          // our slice of slot t (stored at step t-1) is now acked at L3
          if (wv == 0 && l == 0 && t > 0) store_coh4(done + t*64 + bid, 1u);
          first = false;
        }
        u32x4 m4 = hfrag[0];
        #pragma unroll
        for (int kk = 1; kk < 16; ++kk) m4 = umax4(m4, hfrag[kk]);
        uint32_t m01 = m4[0] > m4[1] ? m4[0] : m4[1];
        uint32_t m23 = m4[2] > m4[3] ? m4[2] : m4[3];
        uint32_t m = m01 > m23 ? m01 : m23;
        if (__all(m != 0xFFFFFFFFu)) break;
      }
      __builtin_amdgcn_sched_barrier(0);

      f32x4 a0 = (f32x4){0.f,0.f,0.f,0.f}, a1 = a0, a2 = a0, a3 = a0;
      #pragma unroll
      for (int kk = 0; kk < 16; kk += 4){
        a0 = __builtin_amdgcn_mfma_f32_16x16x32_bf16(*(const bf16x8*)&hfrag[kk  ], bfrag[kk  ], a0, 0, 0, 0);
        a1 = __builtin_amdgcn_mfma_f32_16x16x32_bf16(*(const bf16x8*)&hfrag[kk+1], bfrag[kk+1], a1, 0, 0, 0);
        a2 = __builtin_amdgcn_mfma_f32_16x16x32_bf16(*(const bf16x8*)&hfrag[kk+2], bfrag[kk+2], a2, 0, 0, 0);
        a3 = __builtin_amdgcn_mfma_f32_16x16x32_bf16(*(const bf16x8*)&hfrag[kk+3], bfrag[kk+3], a3, 0, 0, 0);
      }
      f32x4 acc = (a0 + a1) + (a2 + a3);

      if (wv == 1)
        *(f32x4*)&accbuf[((t & 1)*64 + l)*4] = acc;   // partial -> wave0
      __syncthreads();

      if (wv == 0){
        f32x4 o = *(const f32x4*)&accbuf[((t & 1)*64 + l)*4];
        uint16_t* hb = hs2 + (t & 1)*256;
        #pragma unroll
        for (int r = 0; r < 4; ++r){
          int b = lk*4 + r;                           // C/D: row=(l>>4)*4+r, col=l&15
          float hv = tanh_fast(xpreg[r] + acc[r] + o[r]);
          hb[b*16 + lr] = f2bf(hv);
          if (t == NS-1) hfin[b*NH + j0 + lr] = hv;
        }
        asm volatile("s_waitcnt lgkmcnt(0)" ::: "memory");
        __builtin_amdgcn_sched_barrier(0);
        // coalesced write-through store of slot t+1 slice (fire-and-forget)
        int rb = l >> 2, cc = l & 3;
        uint32_t w0 = *(const uint32_t*)&hb[rb*16 + cc*4];
        uint32_t w1 = *(const uint32_t*)&hb[rb*16 + cc*4 + 2];
        char* dst = (char*)hch + (long)(t+1) * NB * NH * 2 + rb * 2048 + j0*2 + cc*8;
        store_coh8(dst, ((uint64_t)w1 << 32) | (uint64_t)w0);
        if (t + 1 < NS){
          #pragma unroll
          for (int r = 0; r < 4; ++r)
            xpreg[r] = xp[((long)(lk*4 + r) * NS + (t+1)) * NH + j0 + lr];
        }
      }
    }
    if (wv == 0){
      asm volatile("s_waitcnt vmcnt(0)" ::: "memory");
      if (l == 0) store_coh4(done + NS*64 + bid, 1u);
    }
    return;
  }

  // ================= logits path (s-major tiles) =================
  uint16_t* As = (uint16_t*)smem;          // 8 KB
  uint16_t* Bs = (uint16_t*)(smem + 8192); // 8 KB
  int w = bid - 64;                        // 0..7999
  int tm = w / 250;                        // s-group (8 steps per tile)
  int tn = w % 250;
  int Mb = tm * 128, Nb = tn * 128;
  int hs = tm * 8 + 8;                     // highest needed slot

  // flag gate: 64 B poll of done[hs][0..63]
  {
    const uint32_t* gp = done + hs*64 + (tid & 63);
    while (true){
      uint32_t f = load_coh4(gp);
      asm volatile("s_waitcnt vmcnt(0)" ::: "memory");
      __builtin_amdgcn_sched_barrier(0);
      if (__syncthreads_count(f == 0u) == 0) break;
      __builtin_amdgcn_s_sleep(16);
    }
  }

  int wv = tid >> 6, l = tid & 63;
  int wm = wv >> 1, wn = wv & 1;
  int lr = l & 15, lk = l >> 4;

  int r0 = tid >> 2, c0 = tid & 3;
  int r1 = r0 + 64;
  // s-major: A row m <-> hchain row m+16 (contiguous!)
  const uint16_t* pa0 = hch + (long)(Mb + r0 + 16) * NH + c0*8;
  const uint16_t* pa1 = hch + (long)(Mb + r1 + 16) * NH + c0*8;
  const uint16_t* pb0 = whobf + (long)(Nb + r0) * NH + c0*8;
  const uint16_t* pb1 = whobf + (long)(Nb + r1) * NH + c0*8;
  int da0 = r0*4 + (c0 ^ (r0 & 3));
  int da1 = r1*4 + (c0 ^ (r1 & 3));

  u32x4 ra0 = *(const u32x4*)pa0;
  u32x4 ra1 = *(const u32x4*)pa1;
  u32x4 rb0 = *(const u32x4*)pb0;
  u32x4 rb1 = *(const u32x4*)pb1;

  f32x4 acc[4][4];
  #pragma unroll
  for (int i = 0; i < 4; ++i)
    #pragma unroll
    for (int j = 0; j < 4; ++j) acc[i][j] = (f32x4){0.f,0.f,0.f,0.f};

  for (int kt = 0; kt < 32; ++kt){
    ((u32x4*)As)[da0] = ra0;
    ((u32x4*)As)[da1] = ra1;
    ((u32x4*)Bs)[da0] = rb0;
    ((u32x4*)Bs)[da1] = rb1;
    __syncthreads();
    if (kt != 31){
      int off = (kt + 1) * 32;
      ra0 = *(const u32x4*)(pa0 + off);
      ra1 = *(const u32x4*)(pa1 + off);
      rb0 = *(const u32x4*)(pb0 + off);
      rb1 = *(const u32x4*)(pb1 + off);
    }
    bf16x8 af[4], bg_[4];
    #pragma unroll
    for (int i = 0; i < 4; ++i){
      int r  = wm*64 + i*16 + lr;
      int rb = wn*64 + i*16 + lr;
      af[i]  = *(const bf16x8*)&((const u32x4*)As)[r*4  + (lk ^ (r  & 3))];
      bg_[i] = *(const bf16x8*)&((const u32x4*)Bs)[rb*4 + (lk ^ (rb & 3))];
    }
    #pragma unroll
    for (int i = 0; i < 4; ++i)
      #pragma unroll
      for (int j = 0; j < 4; ++j)
        acc[i][j] = __builtin_amdgcn_mfma_f32_16x16x32_bf16(af[i], bg_[j], acc[i][j], 0, 0, 0);
    __syncthreads();
  }

  #pragma unroll
  for (int j = 0; j < 4; ++j){
    int col = Nb + wn*64 + j*16 + lr;
    float bias = whob[col];
    #pragma unroll
    for (int i = 0; i < 4; ++i){
      #pragma unroll
      for (int r = 0; r < 4; ++r){
        int m = Mb + wm*64 + i*16 + lk*4 + r;       // m = s*16 + b
        long orow = (long)((m & 15) * 256 + (m >> 4));
        out[orow * NV + col] = acc[i][j][r] + bias;
      }
    }
  }
}

extern "C" void kernel_launch(void* const* d_in, const int* in_sizes, int n_in,
                              void* d_out, int out_size, void* d_ws, size_t ws_size,
                              hipStream_t stream){
  (void)in_sizes; (void)n_in; (void)out_size;
  if (ws_size < (size_t)WS_NEED) return;   // insufficient scratch -> fail loudly (poison stays)

  const int*   ids    = (const int*)  d_in[0];
  const float* hidden = (const float*)d_in[1];
  const float* table  = (const float*)d_in[2];
  const float* wxh    = (const float*)d_in[3];
  const float* bxh    = (const float*)d_in[4];
  const float* whh    = (const float*)d_in[5];
  const float* who    = (const float*)d_in[6];
  const float* whob   = (const float*)d_in[7];

  char* ws = (char*)d_ws;
  float*    xp     = (float*)   (ws + WS_XP);
  uint16_t* hchain = (uint16_t*)(ws + WS_HCH);
  uint16_t* whobf  = (uint16_t*)(ws + WS_WHO);
  uint32_t* done   = (uint32_t*)(ws + WS_FLG);
  float* out    = (float*)d_out;
  float* hfinal = out + (long)NB * NS * NV;   // 131,072,000

  k_init <<<2048,  256, 0, stream>>>(hidden, hchain, done);
  k_cvt  <<<16000, 256, 0, stream>>>(who, (uint32_t*)whobf);
  k_xproj<<<1024,  256, 0, stream>>>(ids, table, wxh, bxh, xp);
  k_fused<<<8064,  256, 0, stream>>>(whh, xp, hchain, whobf, whob, done, out, hfinal);
}